// Round 11
// baseline (138.626 us; speedup 1.0000x reference)
//
#include <hip/hip_runtime.h>
#include <hip/hip_bf16.h>
#include <math.h>

typedef _Float16 half8 __attribute__((ext_vector_type(8)));
typedef _Float16 half4 __attribute__((ext_vector_type(4)));
typedef float f32x4 __attribute__((ext_vector_type(4)));

#define BATCH 100
#define CH    512
#define HWP   256
#define SAMP  (CH * HWP)   // 131072 elems per sample

// ---- K0: W fp32->fp16 (1 MB, ~2 us). Only pre-gemm dispatch left.
__global__ __launch_bounds__(256) void k_convw(const float* __restrict__ W,
                                              _Float16* __restrict__ Wh) {
  int base = blockIdx.x * 1024 + threadIdx.x;
#pragma unroll
  for (int j = 0; j < 4; j++) Wh[base + j * 256] = (_Float16)W[base + j * 256];
}

// ---- K1: batched GEMM + fused exp + denom/raw/u epilogue. TXPOSE DELETED:
// B is staged from fp32 x DIRECTLY, transpose done at ds_write time.
//  - loads: 16 scalar fp32/thread (lanes: c4=ln>>3 rows x p0l=ln&7 consecutive
//    -> 8x 32-B coalesced segments/instr; x sample L2-shared by 8 XCD-blocks)
//  - writes: 4x ds_write_b64 at Bs[p][c4*4]; banks = 16(p&1)+2c4 with
//    p = wv*32+p0l+8k -> p&1 = p0l&1 varies -> 16 pairs x 4 lanes = b64 FLOOR.
//  - frag reads + MFMA loop BYTE-IDENTICAL to the proven R6 path.
//  - raw s_barrier + lgkmcnt(0)-only waits: the 18 staged loads stay in
//    flight across barriers (no vmcnt drain; T14 issue-early/write-late).
// Write-once partials (no atomics, no zero-init): denom_part[b][sub],
// raw_part[b][pt][c]. Support blocks skip the u store entirely.
__global__ __launch_bounds__(256) void k_gemm(const _Float16* __restrict__ Wh,
                                             const float* __restrict__ xf,
                                             const float* __restrict__ bias,
                                             _Float16* __restrict__ u,
                                             float* __restrict__ denom_part,
                                             float* __restrict__ raw_part) {
  __shared__ __align__(16) _Float16 smem[16384];   // 32 KB: As0 Bs0 As1 Bs1 x 4096 halfs
  int bid = blockIdx.x;
  // bijective XCD swizzle (800 % 8 == 0, 100 per XCD)
  int w     = (bid & 7) * 100 + (bid >> 3);
  int batch = w >> 3;
  int sub   = w & 7;
  int ot = sub & 3, pt = sub >> 2;     // o-tile fastest: 4 o-tiles share one x-sample in L2
  int o0 = ot * 128, p0 = pt * 128;
  const float* xb = xf + (size_t)batch * SAMP;     // [c][p] fp32

  int t  = threadIdx.x;
  int wv = t >> 6, ln = t & 63;
  int qd = ln >> 4, r = ln & 15;
  int wm0 = (wv >> 1) * 64, wn0 = (wv & 1) * 64;
  int c4 = ln >> 3, p0l = ln & 7;      // B-staging lane roles
  int pwb = wv * 32 + p0l;             // wave's p base (local)

  half8 areg[2];
  float breg[4][4];                    // [i = c-offset][k = p-step]

  auto LOADT = [&](int kk) {
#pragma unroll
    for (int it = 0; it < 2; it++) {
      int ch = it * 256 + t, row = ch >> 2, qc = ch & 3;
      areg[it] = *(const half8*)(Wh + (size_t)(o0 + row) * 512 + kk + qc * 8);
    }
#pragma unroll
    for (int i = 0; i < 4; i++)
#pragma unroll
      for (int k = 0; k < 4; k++)
        breg[i][k] = xb[(size_t)(kk + c4 * 4 + i) * HWP + p0 + pwb + 8 * k];
  };
  auto WRITET = [&](int q) {
    _Float16* As = smem + q * 8192;
    _Float16* Bs = As + 4096;
#pragma unroll
    for (int it = 0; it < 2; it++) {
      int ch = it * 256 + t, row = ch >> 2, qc = ch & 3;
      *(half8*)(As + row * 32 + qc * 8) = areg[it];
    }
#pragma unroll
    for (int k = 0; k < 4; k++) {
      half4 h;
#pragma unroll
      for (int i = 0; i < 4; i++) h[i] = (_Float16)breg[i][k];
      *(half4*)(Bs + (pwb + 8 * k) * 32 + c4 * 4) = h;   // transposed: [p][c]
    }
  };

  f32x4 acc[4][4] = {};
  LOADT(0);
  WRITET(0);                           // compiler waits the loads here
  asm volatile("s_waitcnt lgkmcnt(0)" ::: "memory");
  __builtin_amdgcn_s_barrier();

  for (int ks = 0; ks < 16; ks++) {
    int q = ks & 1;
    if (ks < 15) LOADT((ks + 1) * 32); // 18 loads in flight, hidden under compute
    const _Float16* As = smem + q * 8192;
    const _Float16* Bs = As + 4096;
    half8 af[4], bf[4];
#pragma unroll
    for (int i = 0; i < 4; i++)
      af[i] = *(const half8*)(As + (wm0 + i * 16 + r) * 32 + qd * 8);
#pragma unroll
    for (int j = 0; j < 4; j++)
      bf[j] = *(const half8*)(Bs + (wn0 + j * 16 + r) * 32 + qd * 8);
#pragma unroll
    for (int i = 0; i < 4; i++)
#pragma unroll
      for (int j = 0; j < 4; j++)
        acc[i][j] = __builtin_amdgcn_mfma_f32_16x16x32_f16(af[i], bf[j], acc[i][j], 0, 0, 0);
    asm volatile("s_waitcnt lgkmcnt(0)" ::: "memory");   // this wave's ds_reads done
    __builtin_amdgcn_s_barrier();     // BAR-A: all waves done reading buf q
    if (ks < 15) WRITET(q ^ 1);       // compiler vmcnt-waits areg/breg
    asm volatile("s_waitcnt lgkmcnt(0)" ::: "memory");   // ds_writes retired
    __builtin_amdgcn_s_barrier();     // BAR-B: buf q^1 ready for next step
  }

  __syncthreads();                     // full drain; smem free for overlay
  float* smr = (float*)smem;           // [128] support cross-wave partials
  float* rs  = ((float*)smem) + 128;   // [4]   denom wave sums

  bool is_supp = (batch % 20) < 5;
  float lsum = 0.f;
  if (!is_supp) {                      // query: store u = x*e (read by k_part)
    _Float16* outb = u + (size_t)batch * SAMP;
#pragma unroll
    for (int i = 0; i < 4; i++) {
#pragma unroll
      for (int rg = 0; rg < 4; rg++) {
        int ol = wm0 + i * 16 + qd * 4 + rg;
        float bv = bias[o0 + ol];
        const float* xrow = xb + (size_t)(o0 + ol) * HWP + p0;   // L1/L2-hot
        _Float16* urow = outb + (size_t)(o0 + ol) * HWP + p0;
#pragma unroll
        for (int j = 0; j < 4; j++) {
          int pl = wn0 + j * 16 + r;
          float ev = __expf(acc[i][j][rg] + bv);
          lsum += ev;
          urow[pl] = (_Float16)(xrow[pl] * ev);
        }
      }
    }
  } else {                             // support: raw_part[b][pt][c] = sum_p x*e
    float s4a[4][4];
#pragma unroll
    for (int i = 0; i < 4; i++) {
#pragma unroll
      for (int rg = 0; rg < 4; rg++) {
        int ol = wm0 + i * 16 + qd * 4 + rg;
        float bv = bias[o0 + ol];
        const float* xrow = xb + (size_t)(o0 + ol) * HWP + p0;
        float s4 = 0.f;
#pragma unroll
        for (int j = 0; j < 4; j++) {
          int pl = wn0 + j * 16 + r;
          float ev = __expf(acc[i][j][rg] + bv);
          lsum += ev;
          s4 += xrow[pl] * ev;
        }
#pragma unroll
        for (int off = 1; off < 16; off <<= 1) s4 += __shfl_xor(s4, off, 64);
        s4a[i][rg] = s4;               // valid at r==0 lanes
        if (wn0 == 0 && r == 0) smr[ol] = s4;
      }
    }
    __syncthreads();                   // block-uniform branch -> legal
    if (wn0 == 64) {
      float* rp = raw_part + (size_t)(batch * 2 + pt) * 512 + o0;
#pragma unroll
      for (int i = 0; i < 4; i++)
#pragma unroll
        for (int rg = 0; rg < 4; rg++) {
          int ol = wm0 + i * 16 + qd * 4 + rg;
          if (r == 0) rp[ol] = s4a[i][rg] + smr[ol];   // write-once
        }
    }
  }
#pragma unroll
  for (int off = 32; off; off >>= 1) lsum += __shfl_down(lsum, off, 64);
  if (ln == 0) rs[wv] = lsum;
  __syncthreads();
  if (t == 0) denom_part[batch * 8 + sub] = rs[0] + rs[1] + rs[2] + rs[3];  // write-once
}

// ---- K4a: per (query n, c-chunk gc of 64): partial dots + qq from u (fp16) ----
// s_l derived from raw_part + denom_part (L2-resident). part [n][gc][6][256].
__global__ __launch_bounds__(256) void k_part(const _Float16* __restrict__ u,
                                             const float* __restrict__ raw_part,
                                             const float* __restrict__ denom_part,
                                             float* __restrict__ part) {
  __shared__ float sd[25];
  __shared__ float s_l[5 * 64];
  int n = blockIdx.x >> 3, gc = blockIdx.x & 7;
  int b = (n / 15) * 20 + 5 + (n % 15);
  int t = threadIdx.x;                // position f
  if (t < 25) {                       // inv denoms of the 25 support batches
    int sb = (t / 5) * 20 + (t % 5);
    float d = 0.f;
#pragma unroll
    for (int s = 0; s < 8; s++) d += denom_part[sb * 8 + s];
    sd[t] = 1.0f / d;
  }
  __syncthreads();
  for (int i = t; i < 320; i += 256) {
    int m = i >> 6, cl = i & 63;
    int c = gc * 64 + cl;
    float s = 0.f;
#pragma unroll
    for (int j = 0; j < 5; j++) {
      int sb = m * 20 + j;
      s += (raw_part[(size_t)(sb * 2) * 512 + c] +
            raw_part[(size_t)(sb * 2 + 1) * 512 + c]) * sd[m * 5 + j];
    }
    s_l[i] = s * (1.0f / 1280.0f);
  }
  __syncthreads();
  const _Float16* ub = u + (size_t)b * SAMP + (size_t)gc * 64 * HWP;
  float dot[5] = {0, 0, 0, 0, 0}, qq = 0.f;
#pragma unroll 8
  for (int c = 0; c < 64; c++) {
    float v = (float)ub[c * HWP + t];
    qq += v * v;
#pragma unroll
    for (int m = 0; m < 5; m++) dot[m] += v * s_l[m * 64 + c];
  }
  float* pp = part + (size_t)(n * 8 + gc) * 6 * 256 + t;
  pp[0 * 256] = dot[0]; pp[1 * 256] = dot[1]; pp[2 * 256] = dot[2];
  pp[3 * 256] = dot[3]; pp[4 * 256] = dot[4]; pp[5 * 256] = qq;
}

// ---- K4b: combine partials -> cosine -> softmax(5) -> spatial mean ----
// prefs[m] from raw_part + denom_part inline.
__global__ __launch_bounds__(256) void k_comb(const float* __restrict__ part,
                                             const float* __restrict__ raw_part,
                                             const float* __restrict__ denom_part,
                                             float* __restrict__ out) {
  int n = blockIdx.x, t = threadIdx.x;   // t = position f
  int wv = t >> 6;
  __shared__ float sd[25];
  __shared__ float prefs[5];
  __shared__ float rsn[4][5];
  if (t < 25) {
    int sb = (t / 5) * 20 + (t % 5);
    float d = 0.f;
#pragma unroll
    for (int s = 0; s < 8; s++) d += denom_part[sb * 8 + s];
    sd[t] = 1.0f / d;
  }
  __syncthreads();
  {
    float sn2[5];
#pragma unroll
    for (int m = 0; m < 5; m++) {
      float s1 = 0.f, s2 = 0.f;
#pragma unroll
      for (int j = 0; j < 5; j++) {
        int sb = m * 20 + j;
        float inv = sd[m * 5 + j];
        s1 += (raw_part[(size_t)(sb * 2) * 512 + t] +
               raw_part[(size_t)(sb * 2 + 1) * 512 + t]) * inv;
        s2 += (raw_part[(size_t)(sb * 2) * 512 + 256 + t] +
               raw_part[(size_t)(sb * 2 + 1) * 512 + 256 + t]) * inv;
      }
      s1 *= (1.0f / 1280.0f); s2 *= (1.0f / 1280.0f);
      sn2[m] = s1 * s1 + s2 * s2;
    }
#pragma unroll
    for (int m = 0; m < 5; m++) {
      float v = sn2[m];
#pragma unroll
      for (int off = 32; off; off >>= 1) v += __shfl_down(v, off, 64);
      sn2[m] = v;
    }
    if ((t & 63) == 0) {
#pragma unroll
      for (int m = 0; m < 5; m++) rsn[wv][m] = sn2[m];
    }
    __syncthreads();
    if (t < 5) prefs[t] =
        10.0f / fmaxf(sqrtf(rsn[0][t] + rsn[1][t] + rsn[2][t] + rsn[3][t]), 1e-8f);
    __syncthreads();
  }
  float dot[5] = {0, 0, 0, 0, 0}, qq = 0.f;
#pragma unroll
  for (int gc = 0; gc < 8; gc++) {
    const float* pp = part + (size_t)(n * 8 + gc) * 6 * 256 + t;
    dot[0] += pp[0 * 256]; dot[1] += pp[1 * 256]; dot[2] += pp[2 * 256];
    dot[3] += pp[3 * 256]; dot[4] += pp[4 * 256]; qq += pp[5 * 256];
  }
  float iqn = 1.0f / fmaxf(sqrtf(qq), 1e-20f);
  float sc[5], mx = -1e30f;
#pragma unroll
  for (int m = 0; m < 5; m++) { sc[m] = dot[m] * prefs[m] * iqn; mx = fmaxf(mx, sc[m]); }
  float p[5], ssum = 0.f;
#pragma unroll
  for (int m = 0; m < 5; m++) { p[m] = __expf(sc[m] - mx); ssum += p[m]; }
  float rr = 1.0f / ssum;
#pragma unroll
  for (int m = 0; m < 5; m++) {
    float v = p[m] * rr;
#pragma unroll
    for (int off = 32; off; off >>= 1) v += __shfl_down(v, off, 64);
    p[m] = v;   // lane0 of each wave holds wave sum
  }
  __shared__ float rs[4][5];
  if ((t & 63) == 0) {
#pragma unroll
    for (int m = 0; m < 5; m++) rs[t >> 6][m] = p[m];
  }
  __syncthreads();
  if (t < 5) out[n * 5 + t] =
      (rs[0][t] + rs[1][t] + rs[2][t] + rs[3][t]) * (1.0f / 256.0f);
}

extern "C" void kernel_launch(void* const* d_in, const int* in_sizes, int n_in,
                              void* d_out, int out_size, void* d_ws, size_t ws_size,
                              hipStream_t stream) {
  const float* x    = (const float*)d_in[0];   // (100,512,16,16)
  const float* W    = (const float*)d_in[1];   // (512,512)
  const float* bias = (const float*)d_in[2];   // (512,)
  float* out = (float*)d_out;                  // (75,5) fp32

  char* ws = (char*)d_ws;
  float*    part   = (float*)   (ws + 0);          //  2,764,800 B
  _Float16* Wh     = (_Float16*)(ws + 2764800);    //    524,288 B
  _Float16* u      = (_Float16*)(ws + 3289088);    // 26,214,400 B (queries only)
  float*    dpart  = (float*)   (ws + 29503488);   //      3,200 B denom_part[100][8]
  float*    rpart  = (float*)   (ws + 29506688);   //    409,600 B raw_part[100][2][512]

  k_convw <<<256, 256, 0, stream>>>(W, Wh);
  k_gemm  <<<800, 256, 0, stream>>>(Wh, x, bias, u, dpart, rpart);
  k_part  <<<600, 256, 0, stream>>>(u, rpart, dpart, part);
  k_comb  <<<75,  256, 0, stream>>>(part, rpart, dpart, out);
}